// Round 4
// baseline (109.060 us; speedup 1.0000x reference)
//
#include <hip/hip_runtime.h>
#include <hip/hip_bf16.h>

#define N_POS 4096
#define C_IN 64
#define IC 32
#define L2E 1.4426950408889634f

typedef float f32x16 __attribute__((ext_vector_type(16)));
typedef short bf16x8 __attribute__((ext_vector_type(8)));
typedef unsigned int uint;
typedef uint uint4v __attribute__((ext_vector_type(4)));
typedef unsigned short ushort;

static __device__ __forceinline__ ushort f2bf(float f) {
    __hip_bfloat16 h = __float2bfloat16(f);
    return __builtin_bit_cast(ushort, h);
}
static __device__ __forceinline__ float bf2f(ushort u) {
    uint v = ((uint)u) << 16;
    return __builtin_bit_cast(float, v);
}
static __device__ __forceinline__ uint packbf2(float lo, float hi) {
    return (uint)f2bf(lo) | ((uint)f2bf(hi) << 16);
}

// ---------------- Stage A: projections -> bf16 MFMA layouts ----------------
// grid (256, 6): y = proj*2 + half16. theta is pre-scaled by log2(e).
__global__ __launch_bounds__(128) void proj_kernel(
    const float* __restrict__ x,
    const float* __restrict__ g_w, const float* __restrict__ g_b,
    const float* __restrict__ th_w, const float* __restrict__ th_b,
    const float* __restrict__ ph_w, const float* __restrict__ ph_b,
    ushort* __restrict__ gcn, ushort* __restrict__ tht, ushort* __restrict__ pht)
{
    int gy = blockIdx.y;
    int pj = gy >> 1, half = gy & 1;
    const float* wsrc = (pj == 0) ? g_w : (pj == 1) ? th_w : ph_w;
    const float* bsrc = (pj == 0) ? g_b : (pj == 1) ? th_b : ph_b;
    __shared__ float w[16][64];
    __shared__ float bias[16];
    int tid = threadIdx.x;
    for (int i = tid; i < 1024; i += 128) w[i >> 6][i & 63] = wsrc[half * 1024 + i];
    if (tid < 16) bias[tid] = bsrc[half * 16 + tid];
    __syncthreads();

    int ng = blockIdx.x * 128 + tid;
    int b = ng >> 12, n = ng & 4095;
    const float* xb = x + (size_t)b * C_IN * N_POS + n;
    float xr[64];
    #pragma unroll
    for (int c = 0; c < 64; c++) xr[c] = xb[(size_t)c * N_POS];

    float acc[16];
    #pragma unroll
    for (int o = 0; o < 16; o++) {
        float a = bias[o];
        const float4* w4 = (const float4*)w[o];
        #pragma unroll
        for (int c4 = 0; c4 < 16; c4++) {
            float4 wv = w4[c4];
            a += wv.x * xr[c4*4+0] + wv.y * xr[c4*4+1]
               + wv.z * xr[c4*4+2] + wv.w * xr[c4*4+3];
        }
        if (pj == 1) a *= L2E;
        acc[o] = a;
    }

    if (pj == 0) {
        #pragma unroll
        for (int c = 0; c < 16; c++)
            gcn[((size_t)(b * IC + half * 16 + c)) * N_POS + n] = f2bf(acc[c]);
    } else {
        ushort* dst = ((pj == 1) ? tht : pht) + ((size_t)(b * N_POS + n)) * IC + half * 16;
        uint4v pk0, pk1;
        #pragma unroll
        for (int i = 0; i < 4; i++) pk0[i] = packbf2(acc[2*i], acc[2*i+1]);
        #pragma unroll
        for (int i = 0; i < 4; i++) pk1[i] = packbf2(acc[8+2*i], acc[8+2*i+1]);
        *(uint4v*)dst = pk0;
        *(uint4v*)(dst + 8) = pk1;
    }
}

// -------- mb prep: keys (mbt) pre-scaled by 32^-0.5 * log2e ----------------
__global__ __launch_bounds__(256) void mbprep_kernel(
    const float* __restrict__ mb, ushort* __restrict__ mbt,
    ushort* __restrict__ mbb)
{
    int i = blockIdx.x * 256 + threadIdx.x;   // 8192
    int c = i >> 8, k = i & 255;
    float v = mb[i];
    mbb[i] = f2bf(v);
    mbt[k * 32 + c] = f2bf(v * (0.17677669529663687f * L2E));
}

// ------------- Stage B: non-local attention, m-split = 4, LDS reduce --------
// grid 1024 blocks x 4 waves: block = (b, qtile); wave s = m-range of 1024.
// Block-local reduction -> normalized bf16 y into ync channels 0..31.
__global__ __launch_bounds__(256) void attn_kernel(
    const ushort* __restrict__ tht, const ushort* __restrict__ pht,
    const ushort* __restrict__ gcn, ushort* __restrict__ ync)
{
    __shared__ float redY[4][32][32];
    __shared__ float redD[4][32];
    int tid = threadIdx.x;
    int s = tid >> 6, lane = tid & 63;
    int bid = blockIdx.x;
    int b = bid & 7;                 // batch -> XCD locality
    int qt = bid >> 3;               // 0..127
    int q0 = qt * 32, mbase = s * 1024;
    int cl = lane & 31, h = lane >> 5;

    const ushort* thp = tht + ((size_t)(b * N_POS + q0 + cl)) * IC + 8 * h;
    bf16x8 thf0 = *(const bf16x8*)thp;
    bf16x8 thf1 = *(const bf16x8*)(thp + 16);

    const ushort* phbase = pht + (size_t)b * N_POS * IC;
    const ushort* gbase  = gcn + ((size_t)(b * IC + cl)) * N_POS;

    f32x16 yacc, zero;
    #pragma unroll
    for (int i = 0; i < 16; i++) { yacc[i] = 0.f; zero[i] = 0.f; }
    float sume = 0.f;

    #pragma unroll 2
    for (int mt = 0; mt < 32; ++mt) {
        int m0 = mbase + mt * 32;
        const ushort* php = phbase + ((size_t)(m0 + cl)) * IC + 8 * h;
        bf16x8 phf0 = *(const bf16x8*)php;
        bf16x8 phf1 = *(const bf16x8*)(php + 16);
        const ushort* gp = gbase + m0 + 8 * h;
        bf16x8 gf0 = *(const bf16x8*)gp;
        bf16x8 gf1 = *(const bf16x8*)(gp + 16);

        // S^T[m][q]; theta pre-scaled by log2e so exp(s) = exp2(sv)
        f32x16 sv = __builtin_amdgcn_mfma_f32_32x32x16_bf16(phf0, thf0, zero, 0, 0, 0);
        sv = __builtin_amdgcn_mfma_f32_32x32x16_bf16(phf1, thf1, sv, 0, 0, 0);

        uint w[8];
        #pragma unroll
        for (int i = 0; i < 8; i++) {
            float p0 = exp2f(sv[2*i]);
            float p1 = exp2f(sv[2*i+1]);
            sume += p0 + p1;
            w[i] = packbf2(p0, p1);
        }
        uint wsw[8];
        #pragma unroll
        for (int i = 0; i < 8; i++) wsw[i] = (uint)__shfl_xor((int)w[i], 32);

        // PV A-fragments (proven round-2 construction)
        uint4v a0, a1;
        a0[0] = h ? wsw[2] : w[0];  a0[1] = h ? wsw[3] : w[1];
        a0[2] = h ? w[2] : wsw[0];  a0[3] = h ? w[3] : wsw[1];
        a1[0] = h ? wsw[6] : w[4];  a1[1] = h ? wsw[7] : w[5];
        a1[2] = h ? w[6] : wsw[4];  a1[3] = h ? w[7] : wsw[5];

        yacc = __builtin_amdgcn_mfma_f32_32x32x16_bf16(
            __builtin_bit_cast(bf16x8, a0), gf0, yacc, 0, 0, 0);
        yacc = __builtin_amdgcn_mfma_f32_32x32x16_bf16(
            __builtin_bit_cast(bf16x8, a1), gf1, yacc, 0, 0, 0);
    }

    // stash partials in LDS
    sume += __shfl_xor(sume, 32);
    if (lane < 32) redD[s][cl] = sume;
    #pragma unroll
    for (int r = 0; r < 16; r++) {
        int q = (r & 3) + 8 * (r >> 2) + 4 * h;
        redY[s][q][cl] = yacc[r];
    }
    __syncthreads();

    // block reduce over the 4 m-splits, normalize, write bf16 y (ch 0..31)
    int q = tid >> 3, c4 = tid & 7;
    float den = redD[0][q] + redD[1][q] + redD[2][q] + redD[3][q];
    float4 v0 = *(const float4*)&redY[0][q][c4 * 4];
    float4 v1 = *(const float4*)&redY[1][q][c4 * 4];
    float4 v2 = *(const float4*)&redY[2][q][c4 * 4];
    float4 v3 = *(const float4*)&redY[3][q][c4 * 4];
    float inv = 1.f / den;
    float r0 = (v0.x + v1.x + v2.x + v3.x) * inv;
    float r1 = (v0.y + v1.y + v2.y + v3.y) * inv;
    float r2 = (v0.z + v1.z + v2.z + v3.z) * inv;
    float r3 = (v0.w + v1.w + v2.w + v3.w) * inv;
    uint pk[2];
    pk[0] = packbf2(r0, r1);
    pk[1] = packbf2(r2, r3);
    *(uint2*)(ync + ((size_t)(b * N_POS + q0 + q)) * 64 + c4 * 4) =
        *(const uint2*)pk;
}

// ------- Stage C: mb attention -> ync channels 32..63 -----------------------
__global__ __launch_bounds__(256) void mb_attn_kernel(
    const ushort* __restrict__ pht, const ushort* __restrict__ mbt,
    const ushort* __restrict__ mbb, ushort* __restrict__ ync)
{
    int tid = threadIdx.x;
    int widx = tid >> 6, lane = tid & 63;
    int gwid = blockIdx.x * 4 + widx;      // 0..1023
    int b = gwid >> 7, qt = gwid & 127;
    int q0 = qt * 32;
    int cl = lane & 31, h = lane >> 5;

    const ushort* php = pht + ((size_t)(b * N_POS + q0 + cl)) * IC + 8 * h;
    bf16x8 qf0 = *(const bf16x8*)php;
    bf16x8 qf1 = *(const bf16x8*)(php + 16);

    f32x16 yacc, zero;
    #pragma unroll
    for (int i = 0; i < 16; i++) { yacc[i] = 0.f; zero[i] = 0.f; }
    float sume = 0.f;

    #pragma unroll 2
    for (int kt = 0; kt < 8; ++kt) {
        int k0 = kt * 32;
        const ushort* ap = mbt + ((size_t)(k0 + cl)) * IC + 8 * h;
        bf16x8 af0 = *(const bf16x8*)ap;
        bf16x8 af1 = *(const bf16x8*)(ap + 16);
        const ushort* bp = mbb + (size_t)cl * 256 + k0 + 8 * h;
        bf16x8 bf0 = *(const bf16x8*)bp;
        bf16x8 bf1 = *(const bf16x8*)(bp + 16);

        f32x16 sv = __builtin_amdgcn_mfma_f32_32x32x16_bf16(af0, qf0, zero, 0, 0, 0);
        sv = __builtin_amdgcn_mfma_f32_32x32x16_bf16(af1, qf1, sv, 0, 0, 0);

        uint w[8];
        #pragma unroll
        for (int i = 0; i < 8; i++) {
            float p0 = exp2f(sv[2*i]);
            float p1 = exp2f(sv[2*i+1]);
            sume += p0 + p1;
            w[i] = packbf2(p0, p1);
        }
        uint wsw[8];
        #pragma unroll
        for (int i = 0; i < 8; i++) wsw[i] = (uint)__shfl_xor((int)w[i], 32);

        uint4v a0, a1;
        a0[0] = h ? wsw[2] : w[0];  a0[1] = h ? wsw[3] : w[1];
        a0[2] = h ? w[2] : wsw[0];  a0[3] = h ? w[3] : wsw[1];
        a1[0] = h ? wsw[6] : w[4];  a1[1] = h ? wsw[7] : w[5];
        a1[2] = h ? w[6] : wsw[4];  a1[3] = h ? w[7] : wsw[5];

        yacc = __builtin_amdgcn_mfma_f32_32x32x16_bf16(
            __builtin_bit_cast(bf16x8, a0), bf0, yacc, 0, 0, 0);
        yacc = __builtin_amdgcn_mfma_f32_32x32x16_bf16(
            __builtin_bit_cast(bf16x8, a1), bf1, yacc, 0, 0, 0);
    }

    sume += __shfl_xor(sume, 32);          // lane q (0..31) holds denom[q]
    ushort* ybase = ync + ((size_t)(b * N_POS + q0)) * 64;
    #pragma unroll
    for (int r = 0; r < 16; r++) {
        int q = (r & 3) + 8 * (r >> 2) + 4 * h;
        float d = __shfl(sume, q);
        ybase[q * 64 + 32 + cl] = f2bf(yacc[r] / d);
    }
}

// ------------- Stage D: out = [W|Wz1] . ync + bias + x ----------------------
__global__ __launch_bounds__(128) void out_kernel(
    const float* __restrict__ x,
    const float* __restrict__ Ww, const float* __restrict__ Wb,
    const float* __restrict__ Wzw, const float* __restrict__ Wzb,
    const ushort* __restrict__ ync, float* __restrict__ out)
{
    int oh = blockIdx.y;
    __shared__ float sWc[32][64];
    __shared__ float sb[32];
    int tid = threadIdx.x;
    for (int i = tid; i < 2048; i += 128) {
        int o = i >> 6, c = i & 63;
        sWc[o][c] = (c < 32) ? Ww[(oh * 32 + o) * 32 + c]
                             : Wzw[(oh * 32 + o) * 32 + (c - 32)];
    }
    if (tid < 32) sb[tid] = Wb[oh * 32 + tid] + Wzb[oh * 32 + tid];
    __syncthreads();

    int ng = blockIdx.x * 128 + tid;
    int b = ng >> 12, n = ng & 4095;
    const ushort* yn = ync + ((size_t)(b * N_POS + n)) * 64;
    float yv[64];
    #pragma unroll
    for (int i8 = 0; i8 < 8; i8++) {
        bf16x8 v = *(const bf16x8*)(yn + i8 * 8);
        #pragma unroll
        for (int j = 0; j < 8; j++) yv[i8 * 8 + j] = bf2f((ushort)v[j]);
    }
    const float* xb = x   + ((size_t)(b * C_IN + oh * 32)) * N_POS + n;
    float*       ob = out + ((size_t)(b * C_IN + oh * 32)) * N_POS + n;
    for (int o = 0; o < 32; o++) {
        float acc = sb[o] + xb[(size_t)o * N_POS];
        const float4* w4 = (const float4*)sWc[o];
        #pragma unroll
        for (int c4 = 0; c4 < 16; c4++) {
            float4 a = w4[c4];
            acc += a.x * yv[c4*4+0] + a.y * yv[c4*4+1]
                 + a.z * yv[c4*4+2] + a.w * yv[c4*4+3];
        }
        ob[(size_t)o * N_POS] = acc;
    }
}

extern "C" void kernel_launch(void* const* d_in, const int* in_sizes, int n_in,
                              void* d_out, int out_size, void* d_ws, size_t ws_size,
                              hipStream_t stream) {
    const float* x    = (const float*)d_in[0];
    const float* g_w  = (const float*)d_in[1];
    const float* g_b  = (const float*)d_in[2];
    const float* th_w = (const float*)d_in[3];
    const float* th_b = (const float*)d_in[4];
    const float* ph_w = (const float*)d_in[5];
    const float* ph_b = (const float*)d_in[6];
    const float* W_w  = (const float*)d_in[7];
    const float* W_b  = (const float*)d_in[8];
    const float* Wz_w = (const float*)d_in[9];
    const float* Wz_b = (const float*)d_in[10];
    const float* mb   = (const float*)d_in[11];
    float* out = (float*)d_out;

    char* w = (char*)d_ws;
    ushort* tht = (ushort*)w;                        // 2 MB
    ushort* pht = (ushort*)(w + (2u << 20));         // 2 MB
    ushort* gcn = (ushort*)(w + (4u << 20));         // 2 MB
    ushort* mbt = (ushort*)(w + (6u << 20));         // 16 KB
    ushort* mbb = (ushort*)(w + (6u << 20) + 16384); // 16 KB
    ushort* ync = (ushort*)(w + (7u << 20));         // 4 MB  [b][n][64]

    proj_kernel<<<dim3(256, 6), 128, 0, stream>>>(x, g_w, g_b, th_w, th_b,
                                                  ph_w, ph_b, gcn, tht, pht);
    mbprep_kernel<<<32, 256, 0, stream>>>(mb, mbt, mbb);
    attn_kernel<<<1024, 256, 0, stream>>>(tht, pht, gcn, ync);
    mb_attn_kernel<<<256, 256, 0, stream>>>(pht, mbt, mbb, ync);
    out_kernel<<<dim3(256, 2), 128, 0, stream>>>(x, W_w, W_b, Wz_w, Wz_b, ync, out);
}